// Round 2
// baseline (809.028 us; speedup 1.0000x reference)
//
#include <hip/hip_runtime.h>

#define T_TOK 4096
#define H_DIM 2048
#define F_DIM 1280
#define NE 12
#define TOTAL_ROWS (2 * T_TOK)
#define NCAT (2 * F_DIM)   // 2560 interleaved w1/w3 rows

typedef float f32x4 __attribute__((ext_vector_type(4)));
typedef short bf16x8 __attribute__((ext_vector_type(8)));

__device__ __forceinline__ unsigned short f2bf(float f) {
    unsigned int u = __float_as_uint(f);
    u += 0x7FFFu + ((u >> 16) & 1u);   // RNE
    return (unsigned short)(u >> 16);
}

// async global->LDS, 16B per lane. LDS dest = wave-uniform base + lane*16.
__device__ __forceinline__ void gl2lds16(const void* g, void* l) {
    __builtin_amdgcn_global_load_lds(
        (const __attribute__((address_space(1))) unsigned int*)g,
        (__attribute__((address_space(3))) unsigned int*)l,
        16, 0, 0);
}

// ---------------- fp32 -> bf16 streaming convert (8 elems/thread) ----------------
__global__ __launch_bounds__(256) void convert_kernel(
    const float* __restrict__ src, unsigned short* __restrict__ dst)
{
    size_t i = ((size_t)blockIdx.x * 256 + threadIdx.x) * 8;
    float4 a = *(const float4*)(src + i);
    float4 b = *(const float4*)(src + i + 4);
    unsigned short o[8];
    o[0] = f2bf(a.x); o[1] = f2bf(a.y); o[2] = f2bf(a.z); o[3] = f2bf(a.w);
    o[4] = f2bf(b.x); o[5] = f2bf(b.y); o[6] = f2bf(b.z); o[7] = f2bf(b.w);
    *(uint4*)(dst + i) = *(const uint4*)o;
}

// ---- w1/w3 -> wcat interleave convert: wcat row = 32*(f>>4) + which*16 + (f&15) ----
// one block per (f, e) row; 256 threads x 8 elems = 2048 = H_DIM
__global__ __launch_bounds__(256) void convert_w13_kernel(
    const float* __restrict__ src, unsigned short* __restrict__ wcat, int which)
{
    int f = blockIdx.y;
    int e = blockIdx.z;
    int dstrow = ((f >> 4) << 5) + which * 16 + (f & 15);
    size_t si = ((size_t)e * F_DIM + f) * H_DIM + threadIdx.x * 8;
    size_t di = ((size_t)e * NCAT + dstrow) * H_DIM + threadIdx.x * 8;
    float4 a = *(const float4*)(src + si);
    float4 b = *(const float4*)(src + si + 4);
    unsigned short o[8];
    o[0] = f2bf(a.x); o[1] = f2bf(a.y); o[2] = f2bf(a.z); o[3] = f2bf(a.w);
    o[4] = f2bf(b.x); o[5] = f2bf(b.y); o[6] = f2bf(b.z); o[7] = f2bf(b.w);
    *(uint4*)(wcat + di) = *(const uint4*)o;
}

// ---------------- gating: fp32 logits, top-2, normalized weights ----------------
__global__ __launch_bounds__(256) void gate_kernel(
    const float* __restrict__ x, const float* __restrict__ gw,
    int* __restrict__ counts, int* __restrict__ top_e, float* __restrict__ top_w)
{
    int gid = blockIdx.x * blockDim.x + threadIdx.x;
    int tok = gid >> 6;
    int lane = threadIdx.x & 63;
    if (tok >= T_TOK) return;
    const float* xr = x + (size_t)tok * H_DIM;
    float4 xs[8];
#pragma unroll
    for (int c = 0; c < 8; ++c) xs[c] = *(const float4*)(xr + c * 256 + lane * 4);
    float acc[NE];
#pragma unroll
    for (int e = 0; e < NE; ++e) {
        const float* gr = gw + (size_t)e * H_DIM;
        float s = 0.f;
#pragma unroll
        for (int c = 0; c < 8; ++c) {
            float4 g = *(const float4*)(gr + c * 256 + lane * 4);
            s += xs[c].x * g.x + xs[c].y * g.y + xs[c].z * g.z + xs[c].w * g.w;
        }
        acc[e] = s;
    }
#pragma unroll
    for (int e = 0; e < NE; ++e) {
#pragma unroll
        for (int off = 32; off > 0; off >>= 1)
            acc[e] += __shfl_xor(acc[e], off, 64);
    }
    if (lane == 0) {
        int b0 = 0;
#pragma unroll
        for (int e = 1; e < NE; ++e) if (acc[e] > acc[b0]) b0 = e;
        int b1 = (b0 == 0) ? 1 : 0;
#pragma unroll
        for (int e = 0; e < NE; ++e) if (e != b0 && acc[e] > acc[b1]) b1 = e;
        float t = __expf(acc[b1] - acc[b0]);   // <= 1
        float w0 = 1.f / (1.f + t);
        top_e[tok * 2] = b0; top_e[tok * 2 + 1] = b1;
        top_w[tok * 2] = w0; top_w[tok * 2 + 1] = 1.f - w0;
        atomicAdd(&counts[b0], 1);
        atomicAdd(&counts[b1], 1);
    }
}

__global__ void scan_kernel(const int* __restrict__ counts, int* __restrict__ offsets,
                            int* __restrict__ cursors)
{
    if (threadIdx.x == 0 && blockIdx.x == 0) {
        int s = 0;
        for (int e = 0; e < NE; ++e) { offsets[e] = s; s += counts[e]; cursors[e] = 0; }
        offsets[NE] = s;
    }
}

__global__ __launch_bounds__(256) void scatter_kernel(
    const int* __restrict__ top_e, const float* __restrict__ top_w,
    const int* __restrict__ offsets, int* __restrict__ cursors,
    int* __restrict__ row_token, float* __restrict__ row_weight,
    int* __restrict__ inv_pos)
{
    int t = blockIdx.x * blockDim.x + threadIdx.x;
    if (t >= T_TOK) return;
#pragma unroll
    for (int s = 0; s < 2; ++s) {
        int e = top_e[t * 2 + s];
        int pos = atomicAdd(&cursors[e], 1);
        int r = offsets[e] + pos;
        row_token[r] = t;
        row_weight[r] = top_w[t * 2 + s];
        inv_pos[t * 2 + s] = r;
    }
}

// =====================================================================
// FFN1: h = silu(x@w1^T) * (x@w3^T) via single GEMM against interleaved wcat.
// BM=128, BN=256 (wcat cols), BK=64, 8 waves (2M x 4N), depth-2 counted-vmcnt
// pipeline, raw barriers, T2 XOR swizzle (pre-swizzled global source).
// =====================================================================
#define NT1 (H_DIM / 64)   // 32

__global__ __launch_bounds__(512, 2) void ffn1_kernel(
    const unsigned short* __restrict__ xb, const unsigned short* __restrict__ wcat,
    const int* __restrict__ counts, const int* __restrict__ offsets,
    const int* __restrict__ row_token, unsigned short* __restrict__ hbuf)
{
    int e = blockIdx.z;
    int cnt = counts[e];
    int m0 = blockIdx.y * 128;
    if (m0 >= cnt) return;
    int base = offsets[e];
    int n0 = blockIdx.x * 256;          // wcat column space [0, 2560)

    __shared__ unsigned short As[2][128 * 64];   // 32 KB
    __shared__ unsigned short Bs[2][256 * 64];   // 64 KB

    int t = threadIdx.x;
    int lane = t & 63;
    int w = t >> 6;                     // 0..7
    int wm = w >> 2, wn = w & 3;        // 2M x 4N
    int lr = lane & 15, lq = lane >> 4;
    int x7 = lr & 7;

    // ---- staging geometry: each gl2lds covers 8 rows x 8 swizzled 16B chunks ----
    int r8 = lane >> 3;                 // 0..7 row within chunk
    int schunk = (lane & 7) ^ r8;       // pre-swizzled source chunk (T2, rule #21)

    const unsigned short* gA[2];
#pragma unroll
    for (int j = 0; j < 2; ++j) {
        int rl = w * 16 + j * 8 + r8;                       // 0..127
        int tok = row_token[base + min(m0 + rl, cnt - 1)];
        gA[j] = xb + (size_t)tok * H_DIM + schunk * 8;
    }
    const unsigned short* gB[4];
#pragma unroll
    for (int j = 0; j < 4; ++j) {
        int rl = w * 32 + j * 8 + r8;                       // 0..255
        gB[j] = wcat + ((size_t)e * NCAT + n0 + rl) * H_DIM + schunk * 8;
    }

    // ---- per-thread LDS fragment offsets (swizzled read side) ----
    int arow[4], brow[4], sl[2];
#pragma unroll
    for (int ms = 0; ms < 4; ++ms) arow[ms] = (wm * 64 + ms * 16 + lr) * 64;
#pragma unroll
    for (int ns = 0; ns < 4; ++ns) brow[ns] = (wn * 64 + ns * 16 + lr) * 64;
    sl[0] = (lq ^ x7) * 8;
    sl[1] = ((4 + lq) ^ x7) * 8;

    f32x4 acc[4][4] = {};

#define STAGE1(buf, kt)                                            \
    do {                                                           \
        int koff = (kt) * 64;                                      \
        gl2lds16(gA[0] + koff, &As[buf][w * 1024]);                \
        gl2lds16(gA[1] + koff, &As[buf][w * 1024 + 512]);          \
        gl2lds16(gB[0] + koff, &Bs[buf][w * 2048]);                \
        gl2lds16(gB[1] + koff, &Bs[buf][w * 2048 + 512]);          \
        gl2lds16(gB[2] + koff, &Bs[buf][w * 2048 + 1024]);         \
        gl2lds16(gB[3] + koff, &Bs[buf][w * 2048 + 1536]);         \
    } while (0)

    STAGE1(0, 0);
    STAGE1(1, 1);

    for (int kt = 0; kt < NT1; ++kt) {
        int cur = kt & 1;
        if (kt < NT1 - 1) asm volatile("s_waitcnt vmcnt(6)" ::: "memory");
        else              asm volatile("s_waitcnt vmcnt(0)" ::: "memory");
        __builtin_amdgcn_s_barrier();
        __builtin_amdgcn_sched_barrier(0);

        const unsigned short* Ac = As[cur];
        const unsigned short* Bc = Bs[cur];
        __builtin_amdgcn_s_setprio(1);
#pragma unroll
        for (int ks = 0; ks < 2; ++ks) {
            bf16x8 af[4], bf[4];
#pragma unroll
            for (int ms = 0; ms < 4; ++ms) af[ms] = *(const bf16x8*)(Ac + arow[ms] + sl[ks]);
#pragma unroll
            for (int ns = 0; ns < 4; ++ns) bf[ns] = *(const bf16x8*)(Bc + brow[ns] + sl[ks]);
#pragma unroll
            for (int ns = 0; ns < 4; ++ns)
#pragma unroll
                for (int ms = 0; ms < 4; ++ms)
                    acc[ms][ns] = __builtin_amdgcn_mfma_f32_16x16x32_bf16(af[ms], bf[ns], acc[ms][ns], 0, 0, 0);
        }
        __builtin_amdgcn_s_setprio(0);
        __builtin_amdgcn_sched_barrier(0);
        __builtin_amdgcn_s_barrier();
        if (kt + 2 < NT1) STAGE1(cur, kt + 2);
    }
#undef STAGE1

    // epilogue: even/odd fragment pair = (w1, w3) for the same 16 h-cols
    int hbase = blockIdx.x * 128 + wn * 32;
#pragma unroll
    for (int ms = 0; ms < 4; ++ms) {
#pragma unroll
        for (int i = 0; i < 4; ++i) {
            int r = wm * 64 + ms * 16 + lq * 4 + i;
            if (m0 + r < cnt) {
                size_t rowoff = (size_t)(base + m0 + r) * F_DIM;
#pragma unroll
                for (int p = 0; p < 2; ++p) {
                    float a = acc[ms][2 * p][i];
                    float b = acc[ms][2 * p + 1][i];
                    float hv = (a / (1.f + __expf(-a))) * b;
                    hbuf[rowoff + hbase + p * 16 + lr] = f2bf(hv);
                }
            }
        }
    }
}

// =====================================================================
// FFN2: ybuf[row] = weight * (h @ w2^T); same pipelined structure.
// BM=128, BN=256, BK=64, K=1280 (NT=20).
// =====================================================================
#define NT2 (F_DIM / 64)   // 20

__global__ __launch_bounds__(512, 2) void ffn2_kernel(
    const unsigned short* __restrict__ hbuf, const unsigned short* __restrict__ w2b,
    const int* __restrict__ counts, const int* __restrict__ offsets,
    const float* __restrict__ row_weight, float* __restrict__ ybuf)
{
    int e = blockIdx.z;
    int cnt = counts[e];
    int m0 = blockIdx.y * 128;
    if (m0 >= cnt) return;
    int base = offsets[e];
    int n0 = blockIdx.x * 256;          // output H columns

    __shared__ unsigned short As[2][128 * 64];
    __shared__ unsigned short Bs[2][256 * 64];

    int t = threadIdx.x;
    int lane = t & 63;
    int w = t >> 6;
    int wm = w >> 2, wn = w & 3;
    int lr = lane & 15, lq = lane >> 4;
    int x7 = lr & 7;

    int r8 = lane >> 3;
    int schunk = (lane & 7) ^ r8;

    const unsigned short* gA[2];
#pragma unroll
    for (int j = 0; j < 2; ++j) {
        int rl = w * 16 + j * 8 + r8;
        gA[j] = hbuf + (size_t)(base + min(m0 + rl, cnt - 1)) * F_DIM + schunk * 8;
    }
    const unsigned short* gB[4];
#pragma unroll
    for (int j = 0; j < 4; ++j) {
        int rl = w * 32 + j * 8 + r8;
        gB[j] = w2b + ((size_t)e * H_DIM + n0 + rl) * F_DIM + schunk * 8;
    }

    int arow[4], brow[4], sl[2];
#pragma unroll
    for (int ms = 0; ms < 4; ++ms) arow[ms] = (wm * 64 + ms * 16 + lr) * 64;
#pragma unroll
    for (int ns = 0; ns < 4; ++ns) brow[ns] = (wn * 64 + ns * 16 + lr) * 64;
    sl[0] = (lq ^ x7) * 8;
    sl[1] = ((4 + lq) ^ x7) * 8;

    f32x4 acc[4][4] = {};

#define STAGE2(buf, kt)                                            \
    do {                                                           \
        int koff = (kt) * 64;                                      \
        gl2lds16(gA[0] + koff, &As[buf][w * 1024]);                \
        gl2lds16(gA[1] + koff, &As[buf][w * 1024 + 512]);          \
        gl2lds16(gB[0] + koff, &Bs[buf][w * 2048]);                \
        gl2lds16(gB[1] + koff, &Bs[buf][w * 2048 + 512]);          \
        gl2lds16(gB[2] + koff, &Bs[buf][w * 2048 + 1024]);         \
        gl2lds16(gB[3] + koff, &Bs[buf][w * 2048 + 1536]);         \
    } while (0)

    STAGE2(0, 0);
    STAGE2(1, 1);

    for (int kt = 0; kt < NT2; ++kt) {
        int cur = kt & 1;
        if (kt < NT2 - 1) asm volatile("s_waitcnt vmcnt(6)" ::: "memory");
        else              asm volatile("s_waitcnt vmcnt(0)" ::: "memory");
        __builtin_amdgcn_s_barrier();
        __builtin_amdgcn_sched_barrier(0);

        const unsigned short* Ac = As[cur];
        const unsigned short* Bc = Bs[cur];
        __builtin_amdgcn_s_setprio(1);
#pragma unroll
        for (int ks = 0; ks < 2; ++ks) {
            bf16x8 af[4], bf[4];
#pragma unroll
            for (int ms = 0; ms < 4; ++ms) af[ms] = *(const bf16x8*)(Ac + arow[ms] + sl[ks]);
#pragma unroll
            for (int ns = 0; ns < 4; ++ns) bf[ns] = *(const bf16x8*)(Bc + brow[ns] + sl[ks]);
#pragma unroll
            for (int ns = 0; ns < 4; ++ns)
#pragma unroll
                for (int ms = 0; ms < 4; ++ms)
                    acc[ms][ns] = __builtin_amdgcn_mfma_f32_16x16x32_bf16(af[ms], bf[ns], acc[ms][ns], 0, 0, 0);
        }
        __builtin_amdgcn_s_setprio(0);
        __builtin_amdgcn_sched_barrier(0);
        __builtin_amdgcn_s_barrier();
        if (kt + 2 < NT2) STAGE2(cur, kt + 2);
    }
#undef STAGE2

#pragma unroll
    for (int ms = 0; ms < 4; ++ms) {
#pragma unroll
        for (int i = 0; i < 4; ++i) {
            int r = wm * 64 + ms * 16 + lq * 4 + i;
            if (m0 + r < cnt) {
                float wgt = row_weight[base + m0 + r];
                size_t rowoff = (size_t)(base + m0 + r) * H_DIM;
#pragma unroll
                for (int ns = 0; ns < 4; ++ns) {
                    int c = n0 + wn * 64 + ns * 16 + lr;
                    ybuf[rowoff + c] = acc[ms][ns][i] * wgt;
                }
            }
        }
    }
}

// ---------------- combine: out[t] = ybuf[pos0] + ybuf[pos1] ----------------
__global__ __launch_bounds__(256) void combine_kernel(
    const float* __restrict__ ybuf, const int* __restrict__ inv_pos,
    float* __restrict__ out)
{
    int tk = blockIdx.x;
    int p0 = inv_pos[2 * tk];
    int p1 = inv_pos[2 * tk + 1];
    const float4* y0 = (const float4*)(ybuf + (size_t)p0 * H_DIM);
    const float4* y1 = (const float4*)(ybuf + (size_t)p1 * H_DIM);
    float4* o = (float4*)(out + (size_t)tk * H_DIM);
#pragma unroll
    for (int i = threadIdx.x; i < H_DIM / 4; i += 256) {
        float4 a = y0[i], b = y1[i];
        float4 r;
        r.x = a.x + b.x; r.y = a.y + b.y; r.z = a.z + b.z; r.w = a.w + b.w;
        o[i] = r;
    }
}

extern "C" void kernel_launch(void* const* d_in, const int* in_sizes, int n_in,
                              void* d_out, int out_size, void* d_ws, size_t ws_size,
                              hipStream_t stream)
{
    const float* x  = (const float*)d_in[0];
    const float* gw = (const float*)d_in[1];
    const float* w1 = (const float*)d_in[2];
    const float* w2 = (const float*)d_in[3];
    const float* w3 = (const float*)d_in[4];
    float* out = (float*)d_out;

    // ---- workspace carve-up ----
    unsigned char* p = (unsigned char*)d_ws;
    int* counts     = (int*)p;  p += 256;
    int* cursors    = (int*)p;  p += 256;
    int* offsets    = (int*)p;  p += 256;
    int* top_e      = (int*)p;  p += 2 * T_TOK * 4;
    float* top_w    = (float*)p; p += 2 * T_TOK * 4;
    int* row_token  = (int*)p;  p += 2 * T_TOK * 4;
    float* row_weight = (float*)p; p += 2 * T_TOK * 4;
    int* inv_pos    = (int*)p;  p += 2 * T_TOK * 4;
    unsigned short* xb  = (unsigned short*)p; p += (size_t)T_TOK * H_DIM * 2;
    unsigned short* w2b = (unsigned short*)p; p += (size_t)NE * H_DIM * F_DIM * 2;
    unsigned short* hb  = (unsigned short*)p; p += (size_t)TOTAL_ROWS * F_DIM * 2;
    // union: wcat (bf16, used through ffn1) overlaps ybuf (fp32, used after)
    unsigned short* wcat = (unsigned short*)p;
    float* ybuf = (float*)p;

    // ---- bf16 conversions ----
    const int WELEM = NE * F_DIM * H_DIM;           // 31,457,280
    convert_kernel<<<T_TOK * H_DIM / 2048, 256, 0, stream>>>(x, xb);
    convert_kernel<<<WELEM / 2048, 256, 0, stream>>>(w2, w2b);
    dim3 gw13(1, F_DIM, NE);
    convert_w13_kernel<<<gw13, 256, 0, stream>>>(w1, wcat, 0);
    convert_w13_kernel<<<gw13, 256, 0, stream>>>(w3, wcat, 1);

    hipMemsetAsync(counts, 0, 64 * sizeof(int), stream);
    gate_kernel<<<T_TOK / 4, 256, 0, stream>>>(x, gw, counts, top_e, top_w);
    scan_kernel<<<1, 64, 0, stream>>>(counts, offsets, cursors);
    scatter_kernel<<<T_TOK / 256, 256, 0, stream>>>(top_e, top_w, offsets, cursors,
                                                    row_token, row_weight, inv_pos);

    dim3 g1(NCAT / 256, 32, NE);    // (10, 32, 12)
    ffn1_kernel<<<g1, 512, 0, stream>>>(xb, wcat, counts, offsets, row_token, hb);

    dim3 g2(H_DIM / 256, 32, NE);   // (8, 32, 12)
    ffn2_kernel<<<g2, 512, 0, stream>>>(hb, w2b, counts, offsets, row_weight, ybuf);

    combine_kernel<<<T_TOK, 256, 0, stream>>>(ybuf, inv_pos, out);
}